// Round 2
// baseline (351.706 us; speedup 1.0000x reference)
//
#include <hip/hip_runtime.h>
#include <hip/hip_bf16.h>

// LinearAttention MI355X: B=16, C=256, n=4096, h=8, d=64, SCALE=0.125
// R7: kv_phi LDS 53,248 -> 32,768 B by time-sharing Bs with Es/Vs
//   (Bs live only in ks loop; Es/Vs only from deposit to phi MFMA).
//   +2 barriers/st fence the union. lb(256,4): 4 blocks/CU resident,
//   grid 1024 = one full round, no tail (R6: 3 blocks + 1-block tail).
//   out_mfma gets lb(256,3) as an occupancy nudge.
//   K0 cvt_w_frag: w_qkv -> wf fragment-major [op][h][w][ks][lane][8]
//   K1 cvt_xT    : xT[b][n][c] = bf16(x[b][c][n])
//   K2a q_gemm   : q GEMM + softmax(d) -> qf fragment-major
//   K2b kv_phi   : k/v GEMM + exp(k) -> swizzled LDS -> phi MFMA; atomics
//   K3 build_M   : Mf (fragment-major) = bf16(w_out · phi / lsum)
//   K4 out_mfma  : out = M · q, LDS-free, all-coalesced fragment loads
// ws layout unchanged from R6.

typedef __attribute__((ext_vector_type(8))) short bf16x8;
typedef __attribute__((ext_vector_type(4))) float f32x4;

__device__ __forceinline__ unsigned short f2bf(float f) {
    union { float f; unsigned int i; } w; w.f = f;
    unsigned int r = w.i + 0x7FFFu + ((w.i >> 16) & 1u);
    return (unsigned short)(r >> 16);
}

// ---------------- K0: w_qkv -> fragment-major bf16 ----------------
// granule g: lane=g&63, ks=(g>>6)&7, w2=(g>>9)&3, h=(g>>11)&7, op=g>>14
__global__ __launch_bounds__(256) void cvt_w_frag(
    const float* __restrict__ wqkv, unsigned short* __restrict__ wf)
{
    int g = blockIdx.x * 256 + threadIdx.x;    // 49152 granules, grid 192
    int lane = g & 63;
    int ks   = (g >> 6) & 7;
    int w2   = (g >> 9) & 3;
    int h    = (g >> 11) & 7;
    int op   = g >> 14;
    int row = op * 512 + h * 64 + w2 * 16 + (lane & 15);
    int col = ks * 32 + (lane >> 4) * 8;
    const float* src = &wqkv[(size_t)row * 256 + col];
    float4 f0 = *(const float4*)&src[0];
    float4 f1 = *(const float4*)&src[4];
    unsigned short t[8] = {f2bf(f0.x), f2bf(f0.y), f2bf(f0.z), f2bf(f0.w),
                           f2bf(f1.x), f2bf(f1.y), f2bf(f1.z), f2bf(f1.w)};
    *(uint4*)&wf[(size_t)g * 8] = *(uint4*)t;
}

// ---------------- K1: x[b][c][n] f32 -> xT[b][n][c] bf16 ----------------
__global__ __launch_bounds__(256) void cvt_xT(
    const float* __restrict__ x, unsigned short* __restrict__ xT)
{
    const int nb = blockIdx.x * 64, cb = blockIdx.y * 64, b = blockIdx.z;
    __shared__ float Ts[64 * 65];
    const int tid = threadIdx.x;
    const int l = tid & 63, w = tid >> 6;
    const float* xb = x + ((size_t)b * 256 + cb) * 4096 + nb;
#pragma unroll
    for (int p = 0; p < 4; p++) {
        int c = p * 16 + (tid >> 4);
        int n4 = (tid & 15) * 4;
        float4 v = *(const float4*)&xb[(size_t)c * 4096 + n4];
        Ts[c * 65 + n4 + 0] = v.x; Ts[c * 65 + n4 + 1] = v.y;
        Ts[c * 65 + n4 + 2] = v.z; Ts[c * 65 + n4 + 3] = v.w;
    }
    __syncthreads();
    unsigned short t[16];
#pragma unroll
    for (int i = 0; i < 16; i++) t[i] = f2bf(Ts[(w * 16 + i) * 65 + l]);
    unsigned short* dst = xT + ((size_t)b * 4096 + nb + l) * 256 + cb + w * 16;
    *(uint4*)&dst[0] = *(uint4*)&t[0];
    *(uint4*)&dst[8] = *(uint4*)&t[8];
}

// ---------------- K2a: q GEMM + softmax(d) -> qf ----------------
// grid (8 ch, 8 h, 16 b), block 256 (4 waves)
// LDS 20,992 B. Bs [2][128][40] | red (640 f32, aliases Bs buf0 — buf0
// dead after ks=6 barrier) | Qs [128][72] at +2560B (aliases Bs tail —
// written only after S3, when all buf1 reads drained at S2).
__global__ __launch_bounds__(256, 3) void q_gemm(
    const unsigned short* __restrict__ xT, const unsigned short* __restrict__ wf,
    unsigned short* __restrict__ qf)
{
    const int ch = blockIdx.x;
    const int h  = blockIdx.y;
    const int b  = blockIdx.z;
    const int tid  = threadIdx.x;
    const int lane = tid & 63;
    const int w    = tid >> 6;
    const int quad = lane >> 4;
    const int l15  = lane & 15;

    __shared__ unsigned short smem[10496];     // 20,992 B
    unsigned short* Bs = smem;                 // [2][128][40]
    float* red = (float*)smem;                 // 640 f32 (aliases buf0)
    unsigned short* Qs = smem + 1280;          // [128][72]

    const unsigned short* wfq = wf + ((size_t)((0 * 8 + h) * 4 + w) * 8) * 512 + lane * 8;

    const int srow = tid >> 1;                 // staging row 0..127
    const int sch  = (tid & 1) * 16;           // 0/16 shorts (32 B per thread)

    for (int st = 0; st < 4; st++) {
        const int nb = ch * 512 + st * 128;
        const unsigned short* xrow =
            xT + ((size_t)b * 4096 + nb + srow) * 256 + sch;

        f32x4 accq[8];
#pragma unroll
        for (int i = 0; i < 8; i++) accq[i] = (f32x4)(0.f);

        {
            uint4 p0 = *(const uint4*)&xrow[0];
            uint4 p1 = *(const uint4*)&xrow[8];
            unsigned short* bw = Bs + srow * 40 + sch;
            *(uint4*)&bw[0] = p0;
            *(uint4*)&bw[8] = p1;
        }
        __syncthreads();

        for (int ks = 0; ks < 8; ks++) {
            const int buf = ks & 1;
            uint4 n0, n1;
            if (ks < 7) {
                n0 = *(const uint4*)&xrow[(ks + 1) * 32];
                n1 = *(const uint4*)&xrow[(ks + 1) * 32 + 8];
            }
            bf16x8 aq = *(const bf16x8*)&wfq[ks * 512];
            const unsigned short* bsr = Bs + buf * 5120 + l15 * 40 + quad * 8;
#pragma unroll
            for (int nt = 0; nt < 8; nt++) {
                bf16x8 bv = *(const bf16x8*)&bsr[nt * 640];   // 16 rows * 40
                accq[nt] = __builtin_amdgcn_mfma_f32_16x16x32_bf16(aq, bv, accq[nt], 0, 0, 0);
            }
            if (ks < 7) {
                unsigned short* bw = Bs + (buf ^ 1) * 5120 + srow * 40 + sch;
                *(uint4*)&bw[0] = n0;
                *(uint4*)&bw[8] = n1;
                __syncthreads();
            }
        }

        // ---- softmax over d (64 rows) -> qf fragment-major ----
#pragma unroll
        for (int nt = 0; nt < 8; nt++) {
#pragma unroll
            for (int r = 0; r < 4; r++) accq[nt][r] = __expf(accq[nt][r]);
            float s = accq[nt][0] + accq[nt][1] + accq[nt][2] + accq[nt][3];
            s += __shfl_xor(s, 16);
            s += __shfl_xor(s, 32);
            if (quad == 0) red[w * 128 + nt * 16 + l15] = s;
        }
        __syncthreads();                       // S2 (also drains buf1 reads)
        if (tid < 128) {
            float t = red[tid] + red[128 + tid] + red[256 + tid] + red[384 + tid];
            red[512 + tid] = 0.125f / t;
        }
        __syncthreads();                       // S3
#pragma unroll
        for (int nt = 0; nt < 8; nt++) {
            float li = red[512 + nt * 16 + l15];
            uint2 pp;
            pp.x = (unsigned int)f2bf(accq[nt][0] * li) |
                   ((unsigned int)f2bf(accq[nt][1] * li) << 16);
            pp.y = (unsigned int)f2bf(accq[nt][2] * li) |
                   ((unsigned int)f2bf(accq[nt][3] * li) << 16);
            *(uint2*)&Qs[(nt * 16 + l15) * 72 + w * 16 + quad * 4] = pp;
        }
        __syncthreads();                       // S4
        {
            // qf granule: ((((b*32+nbIdx)*16 + ks)*8 + nt)*64 + quad*16 + l15)
            const int n = tid >> 1, half = tid & 1;
            const int nbIdx = ch * 4 + st;
            const int ksq = h * 2 + half;
            const size_t gbase =
                (((size_t)(b * 32 + nbIdx) * 16 + ksq) * 8 + (n >> 4)) * 64 + (n & 15);
#pragma unroll
            for (int u = 0; u < 4; u++)
                *(uint4*)&qf[(gbase + u * 16) * 8] = *(uint4*)&Qs[n * 72 + half * 32 + u * 8];
        }
        __syncthreads();                       // S5: Qs/red dead before next Bs write
    }
}

// ---------------- K2b: k/v GEMM + exp(k) + phi ----------------
// grid (8 ch, 8 h, 16 b), block 256 (4 waves)
// LDS 32,768 B: Es[64][128] | Vs[64][128] ; Bs[2][128][40] ALIASES the
// Es/Vs region (live only during ks loop; Es/Vs live only from the
// post-ks deposit through the phi MFMA). Fences:
//   SA (st top)     : phi reads of st-1 done before Bs staging write
//   (in-loop dbuf barriers unchanged)
//   SB (post ks)    : last Bs MFMA reads done before Es/Vs deposits
//   S6 (post depos) : deposits visible before phi MFMA reads
// 4 blocks/CU resident (32KB LDS, <=128 VGPR) -> grid 1024 = 1 round.
__global__ __launch_bounds__(256, 4) void kv_phi(
    const unsigned short* __restrict__ xT, const unsigned short* __restrict__ wf,
    float* __restrict__ phi, float* __restrict__ lsum)
{
    const int ch = blockIdx.x;
    const int h  = blockIdx.y;
    const int b  = blockIdx.z;
    const int tid  = threadIdx.x;
    const int lane = tid & 63;
    const int w    = tid >> 6;
    const int quad = lane >> 4;
    const int l15  = lane & 15;

    __shared__ unsigned short smem[16384];     // 32,768 B
    unsigned short* Es = smem;                 // [64][128]
    unsigned short* Vs = smem + 8192;          // [64][128]
    unsigned short* Bs = smem;                 // [2][128][40] (aliases Es/Vs)

    const unsigned short* wfk = wf + ((size_t)((1 * 8 + h) * 4 + w) * 8) * 512 + lane * 8;
    const unsigned short* wfv = wf + ((size_t)((2 * 8 + h) * 4 + w) * 8) * 512 + lane * 8;

    f32x4 pacc[4];
#pragma unroll
    for (int i = 0; i < 4; i++) pacc[i] = (f32x4)(0.f);
    float lacc[4] = {0.f, 0.f, 0.f, 0.f};

    const int srow = tid >> 1;
    const int sch  = (tid & 1) * 16;

    for (int st = 0; st < 4; st++) {
        const int nb = ch * 512 + st * 128;
        const unsigned short* xrow =
            xT + ((size_t)b * 4096 + nb + srow) * 256 + sch;

        f32x4 acck[8], accv[8];
#pragma unroll
        for (int i = 0; i < 8; i++) {
            acck[i] = (f32x4)(0.f); accv[i] = (f32x4)(0.f);
        }

        __syncthreads();                       // SA: phi reads (st-1) done
        {
            uint4 p0 = *(const uint4*)&xrow[0];
            uint4 p1 = *(const uint4*)&xrow[8];
            unsigned short* bw = Bs + srow * 40 + sch;
            *(uint4*)&bw[0] = p0;
            *(uint4*)&bw[8] = p1;
        }
        __syncthreads();

        for (int ks = 0; ks < 8; ks++) {
            const int buf = ks & 1;
            uint4 n0, n1;
            if (ks < 7) {
                n0 = *(const uint4*)&xrow[(ks + 1) * 32];
                n1 = *(const uint4*)&xrow[(ks + 1) * 32 + 8];
            }
            bf16x8 ak = *(const bf16x8*)&wfk[ks * 512];
            bf16x8 av = *(const bf16x8*)&wfv[ks * 512];
            const unsigned short* bsr = Bs + buf * 5120 + l15 * 40 + quad * 8;
#pragma unroll
            for (int nt = 0; nt < 8; nt++) {
                bf16x8 bv = *(const bf16x8*)&bsr[nt * 640];
                acck[nt] = __builtin_amdgcn_mfma_f32_16x16x32_bf16(ak, bv, acck[nt], 0, 0, 0);
                accv[nt] = __builtin_amdgcn_mfma_f32_16x16x32_bf16(av, bv, accv[nt], 0, 0, 0);
            }
            if (ks < 7) {
                unsigned short* bw = Bs + (buf ^ 1) * 5120 + srow * 40 + sch;
                *(uint4*)&bw[0] = n0;
                *(uint4*)&bw[8] = n1;
                __syncthreads();
            }
        }
        __syncthreads();                       // SB: Bs reads done

        // ---- k/v epilogue: exp, lsum partials, swizzled deposit ----
#pragma unroll
        for (int r = 0; r < 4; r++) {
            const int dl = quad * 4 + r;                            // d & 15
            const int dbase = (w * 16 + dl) * 256 + (l15 & 7) * 2;  // byte off
#pragma unroll
            for (int nt = 0; nt < 8; nt++) {
                const int pos = (2 * nt + (l15 >> 3)) ^ dl;
                float ek = __expf(acck[nt][r]);
                lacc[r] += ek;
                *(unsigned short*)((char*)Es + dbase + pos * 16) = f2bf(ek);
                *(unsigned short*)((char*)Vs + dbase + pos * 16) = f2bf(accv[nt][r]);
            }
        }
        __syncthreads();                       // S6

        // phi MFMA: phi[d][e] += sum_n expk[d][n] v[e][n], K=128
#pragma unroll
        for (int k2 = 0; k2 < 4; k2++) {
            bf16x8 ae = *(bf16x8*)((char*)Es + (w * 16 + l15) * 256 +
                                   (((k2 * 4 + quad) ^ l15) * 16));
#pragma unroll
            for (int et = 0; et < 4; et++) {
                bf16x8 bv = *(bf16x8*)((char*)Vs + (et * 16 + l15) * 256 +
                                       (((k2 * 4 + quad) ^ l15) * 16));
                pacc[et] = __builtin_amdgcn_mfma_f32_16x16x32_bf16(ae, bv, pacc[et], 0, 0, 0);
            }
        }
        // next st: SA fences Es/Vs reads before new Bs staging
    }

    // lsum: reduce over l15 then one atomic per d-row
#pragma unroll
    for (int r = 0; r < 4; r++) {
        float s = lacc[r];
        s += __shfl_xor(s, 1); s += __shfl_xor(s, 2);
        s += __shfl_xor(s, 4); s += __shfl_xor(s, 8);
        if (l15 == 0)
            atomicAdd(&lsum[((size_t)b * 8 + h) * 64 + w * 16 + quad * 4 + r], s);
    }
    float* pp = phi + ((size_t)b * 8 + h) * 4096;
#pragma unroll
    for (int et = 0; et < 4; et++)
#pragma unroll
        for (int r = 0; r < 4; r++)
            atomicAdd(&pp[(w * 16 + quad * 4 + r) * 64 + et * 16 + l15], pacc[et][r]);
}

// ---------------- K3: Mf = w_out · (phi/l), fragment-major bf16 ----------------
// grid (8 h, 16 b), block 256 (thread = c)
__global__ __launch_bounds__(256) void build_M(
    const float* __restrict__ phi, const float* __restrict__ lsum,
    const float* __restrict__ w_out, unsigned short* __restrict__ Mf)
{
    const int h = blockIdx.x, b = blockIdx.y;
    __shared__ float pT[64][68];  // [e][d]
    const float* pp = phi + ((size_t)b * 8 + h) * 4096;  // [d][e]
    const int tid = threadIdx.x;
    const int row = tid >> 2, ls = tid & 3;
#pragma unroll
    for (int u = 0; u < 4; u++) {
        int e0 = (ls + u * 4) * 4;
        float4 v = *(const float4*)&pp[row * 64 + e0];
        pT[e0 + 0][row] = v.x; pT[e0 + 1][row] = v.y;
        pT[e0 + 2][row] = v.z; pT[e0 + 3][row] = v.w;
    }
    __syncthreads();
    const int c = tid;
    float acc[64];
#pragma unroll
    for (int d = 0; d < 64; d++) acc[d] = 0.f;
    for (int e4 = 0; e4 < 16; e4++) {
        float4 wv = *(const float4*)&w_out[(size_t)c * 512 + h * 64 + e4 * 4];
        float wq[4] = {wv.x, wv.y, wv.z, wv.w};
#pragma unroll
        for (int qq = 0; qq < 4; qq++) {
            int e = e4 * 4 + qq;
#pragma unroll
            for (int d4 = 0; d4 < 16; d4++) {
                float4 p = *(const float4*)&pT[e][d4 * 4];
                acc[d4 * 4 + 0] += wq[qq] * p.x;
                acc[d4 * 4 + 1] += wq[qq] * p.y;
                acc[d4 * 4 + 2] += wq[qq] * p.z;
                acc[d4 * 4 + 3] += wq[qq] * p.w;
            }
        }
    }
    const float* lrow = lsum + ((size_t)b * 8 + h) * 64;
    unsigned short tmp[64];
#pragma unroll
    for (int d = 0; d < 64; d++) tmp[d] = f2bf(acc[d] / lrow[d]);
    // Mf granule: ((((b*2+ct)*2+wr)*4+mi)*16 + ks)*64 + quad*16 + l15c
    const int ct = c >> 7, wr = (c >> 6) & 1, mi = (c >> 4) & 3, l15c = c & 15;
#pragma unroll
    for (int u = 0; u < 8; u++) {
        const int ksA = h * 2 + (u >> 2);
        const int quadA = u & 3;
        size_t gidx = ((((size_t)(b * 2 + ct) * 2 + wr) * 4 + mi) * 16 + ksA) * 64
                      + quadA * 16 + l15c;
        *(uint4*)&Mf[gidx * 8] = *(uint4*)&tmp[u * 8];
    }
}

// ---------------- K4: out = M · q, LDS-free, all-coalesced ----------------
// grid (32 nblocks, 2 ctiles, 16 b), block 256 (4 waves, 2x2)
__global__ __launch_bounds__(256, 3) void out_mfma(
    const unsigned short* __restrict__ Mf, const unsigned short* __restrict__ qf,
    float* __restrict__ out)
{
    const int nbIdx = blockIdx.x;
    const int ct    = blockIdx.y;
    const int b     = blockIdx.z;
    const int tid  = threadIdx.x;
    const int lane = tid & 63;
    const int w    = tid >> 6;
    const int wr   = w >> 1, wc = w & 1;
    const int quad = lane >> 4;
    const int l15  = lane & 15;

    f32x4 acc[4][4];
#pragma unroll
    for (int i = 0; i < 4; i++)
#pragma unroll
        for (int j = 0; j < 4; j++) acc[i][j] = (f32x4)(0.f);

    const unsigned short* Ab =
        Mf + ((((size_t)(b * 2 + ct) * 2 + wr) * 4) * 16) * 512 + lane * 8;
    const unsigned short* Bb =
        qf + (((size_t)(b * 32 + nbIdx) * 16) * 8) * 512 + lane * 8;

    for (int ks = 0; ks < 16; ks++) {
        bf16x8 af[4], bv[4];
#pragma unroll
        for (int mi = 0; mi < 4; mi++)
            af[mi] = *(const bf16x8*)&Ab[(size_t)(mi * 16 + ks) * 512];
#pragma unroll
        for (int ni = 0; ni < 4; ni++)
            bv[ni] = *(const bf16x8*)&Bb[(size_t)(ks * 8 + wc * 4 + ni) * 512];
#pragma unroll
        for (int mi = 0; mi < 4; mi++)
#pragma unroll
            for (int ni = 0; ni < 4; ni++)
                acc[mi][ni] = __builtin_amdgcn_mfma_f32_16x16x32_bf16(
                    af[mi], bv[ni], acc[mi][ni], 0, 0, 0);
    }
    float* ob = out + ((size_t)b * 256 + ct * 128 + wr * 64) * 4096
                + nbIdx * 128 + wc * 64;
#pragma unroll
    for (int mi = 0; mi < 4; mi++)
#pragma unroll
        for (int ni = 0; ni < 4; ni++)
#pragma unroll
            for (int r = 0; r < 4; r++)
                ob[(size_t)(mi * 16 + quad * 4 + r) * 4096 + ni * 16 + l15]
                    = acc[mi][ni][r];
}

extern "C" void kernel_launch(void* const* d_in, const int* in_sizes, int n_in,
                              void* d_out, int out_size, void* d_ws, size_t ws_size,
                              hipStream_t stream) {
    const float* x     = (const float*)d_in[0];
    const float* w_qkv = (const float*)d_in[1];
    const float* w_out = (const float*)d_in[2];
    float* out = (float*)d_out;

    char* ws = (char*)d_ws;
    unsigned short* qf = (unsigned short*)ws;                     // 67,108,864 B
    unsigned short* wf = (unsigned short*)(ws + 67108864);        //    786,432 B
    float* lsum = (float*)(ws + 67895296);                        //     32,768 B
    float* phi  = (float*)(ws + 67928064);                        //  2,097,152 B
    unsigned short* Mf = (unsigned short*)(ws + 70025216);        //  4,194,304 B
    unsigned short* xT = (unsigned short*)(ws + 74219520);        // 33,554,432 B
    // total ws: 107,773,952 B (same as R6, proven safe)

    hipMemsetAsync(lsum, 0, (8192 + 524288) * sizeof(float), stream);

    cvt_w_frag<<<192, 256, 0, stream>>>(w_qkv, wf);
    cvt_xT<<<dim3(64, 4, 16), 256, 0, stream>>>(x, xT);
    q_gemm<<<dim3(8, 8, 16), 256, 0, stream>>>(xT, wf, qf);
    kv_phi<<<dim3(8, 8, 16), 256, 0, stream>>>(xT, wf, phi, lsum);
    build_M<<<dim3(8, 16), 256, 0, stream>>>(phi, lsum, w_out, Mf);
    out_mfma<<<dim3(32, 2, 16), 256, 0, stream>>>(Mf, qf, out);
}

// Round 3
// 280.907 us; speedup vs baseline: 1.2520x; 1.2520x over previous
//
#include <hip/hip_runtime.h>
#include <hip/hip_bf16.h>

// LinearAttention MI355X: B=16, C=256, n=4096, h=8, d=64, SCALE=0.125
// R8: R7's 32KB LDS time-share was right; its lb(256,4) was wrong — the
//   128-reg cap made the compiler spill the 64 f32 k/v accumulators to
//   scratch (VGPR 116->64, FETCH 18MB->208MB, WRITE 176MB). Revert the
//   bound to lb(256,2): compiler uses ~116 VGPR (proven in R6, no spill),
//   and runtime residency = min(LDS 160/32=5, VGPR 116<=128 -> 4 blk,
//   slots 8) = 4 blocks/CU, grid 1024 = one round, no tail.
//   K0 cvt_w_frag: w_qkv -> wf fragment-major [op][h][w][ks][lane][8]
//   K1 cvt_xT    : xT[b][n][c] = bf16(x[b][c][n])
//   K2a q_gemm   : q GEMM + softmax(d) -> qf fragment-major
//   K2b kv_phi   : k/v GEMM + exp(k) -> swizzled LDS -> phi MFMA; atomics
//   K3 build_M   : Mf (fragment-major) = bf16(w_out · phi / lsum)
//   K4 out_mfma  : out = M · q, LDS-free, all-coalesced fragment loads
// ws layout unchanged from R6.

typedef __attribute__((ext_vector_type(8))) short bf16x8;
typedef __attribute__((ext_vector_type(4))) float f32x4;

__device__ __forceinline__ unsigned short f2bf(float f) {
    union { float f; unsigned int i; } w; w.f = f;
    unsigned int r = w.i + 0x7FFFu + ((w.i >> 16) & 1u);
    return (unsigned short)(r >> 16);
}

// ---------------- K0: w_qkv -> fragment-major bf16 ----------------
// granule g: lane=g&63, ks=(g>>6)&7, w2=(g>>9)&3, h=(g>>11)&7, op=g>>14
__global__ __launch_bounds__(256) void cvt_w_frag(
    const float* __restrict__ wqkv, unsigned short* __restrict__ wf)
{
    int g = blockIdx.x * 256 + threadIdx.x;    // 49152 granules, grid 192
    int lane = g & 63;
    int ks   = (g >> 6) & 7;
    int w2   = (g >> 9) & 3;
    int h    = (g >> 11) & 7;
    int op   = g >> 14;
    int row = op * 512 + h * 64 + w2 * 16 + (lane & 15);
    int col = ks * 32 + (lane >> 4) * 8;
    const float* src = &wqkv[(size_t)row * 256 + col];
    float4 f0 = *(const float4*)&src[0];
    float4 f1 = *(const float4*)&src[4];
    unsigned short t[8] = {f2bf(f0.x), f2bf(f0.y), f2bf(f0.z), f2bf(f0.w),
                           f2bf(f1.x), f2bf(f1.y), f2bf(f1.z), f2bf(f1.w)};
    *(uint4*)&wf[(size_t)g * 8] = *(uint4*)t;
}

// ---------------- K1: x[b][c][n] f32 -> xT[b][n][c] bf16 ----------------
__global__ __launch_bounds__(256) void cvt_xT(
    const float* __restrict__ x, unsigned short* __restrict__ xT)
{
    const int nb = blockIdx.x * 64, cb = blockIdx.y * 64, b = blockIdx.z;
    __shared__ float Ts[64 * 65];
    const int tid = threadIdx.x;
    const int l = tid & 63, w = tid >> 6;
    const float* xb = x + ((size_t)b * 256 + cb) * 4096 + nb;
#pragma unroll
    for (int p = 0; p < 4; p++) {
        int c = p * 16 + (tid >> 4);
        int n4 = (tid & 15) * 4;
        float4 v = *(const float4*)&xb[(size_t)c * 4096 + n4];
        Ts[c * 65 + n4 + 0] = v.x; Ts[c * 65 + n4 + 1] = v.y;
        Ts[c * 65 + n4 + 2] = v.z; Ts[c * 65 + n4 + 3] = v.w;
    }
    __syncthreads();
    unsigned short t[16];
#pragma unroll
    for (int i = 0; i < 16; i++) t[i] = f2bf(Ts[(w * 16 + i) * 65 + l]);
    unsigned short* dst = xT + ((size_t)b * 4096 + nb + l) * 256 + cb + w * 16;
    *(uint4*)&dst[0] = *(uint4*)&t[0];
    *(uint4*)&dst[8] = *(uint4*)&t[8];
}

// ---------------- K2a: q GEMM + softmax(d) -> qf ----------------
// grid (8 ch, 8 h, 16 b), block 256 (4 waves)
// LDS 20,992 B. Bs [2][128][40] | red (640 f32, aliases Bs buf0 — buf0
// dead after ks=6 barrier) | Qs [128][72] at +2560B (aliases Bs tail —
// written only after S3, when all buf1 reads drained at S2).
__global__ __launch_bounds__(256, 3) void q_gemm(
    const unsigned short* __restrict__ xT, const unsigned short* __restrict__ wf,
    unsigned short* __restrict__ qf)
{
    const int ch = blockIdx.x;
    const int h  = blockIdx.y;
    const int b  = blockIdx.z;
    const int tid  = threadIdx.x;
    const int lane = tid & 63;
    const int w    = tid >> 6;
    const int quad = lane >> 4;
    const int l15  = lane & 15;

    __shared__ unsigned short smem[10496];     // 20,992 B
    unsigned short* Bs = smem;                 // [2][128][40]
    float* red = (float*)smem;                 // 640 f32 (aliases buf0)
    unsigned short* Qs = smem + 1280;          // [128][72]

    const unsigned short* wfq = wf + ((size_t)((0 * 8 + h) * 4 + w) * 8) * 512 + lane * 8;

    const int srow = tid >> 1;                 // staging row 0..127
    const int sch  = (tid & 1) * 16;           // 0/16 shorts (32 B per thread)

    for (int st = 0; st < 4; st++) {
        const int nb = ch * 512 + st * 128;
        const unsigned short* xrow =
            xT + ((size_t)b * 4096 + nb + srow) * 256 + sch;

        f32x4 accq[8];
#pragma unroll
        for (int i = 0; i < 8; i++) accq[i] = (f32x4)(0.f);

        {
            uint4 p0 = *(const uint4*)&xrow[0];
            uint4 p1 = *(const uint4*)&xrow[8];
            unsigned short* bw = Bs + srow * 40 + sch;
            *(uint4*)&bw[0] = p0;
            *(uint4*)&bw[8] = p1;
        }
        __syncthreads();

        for (int ks = 0; ks < 8; ks++) {
            const int buf = ks & 1;
            uint4 n0, n1;
            if (ks < 7) {
                n0 = *(const uint4*)&xrow[(ks + 1) * 32];
                n1 = *(const uint4*)&xrow[(ks + 1) * 32 + 8];
            }
            bf16x8 aq = *(const bf16x8*)&wfq[ks * 512];
            const unsigned short* bsr = Bs + buf * 5120 + l15 * 40 + quad * 8;
#pragma unroll
            for (int nt = 0; nt < 8; nt++) {
                bf16x8 bv = *(const bf16x8*)&bsr[nt * 640];   // 16 rows * 40
                accq[nt] = __builtin_amdgcn_mfma_f32_16x16x32_bf16(aq, bv, accq[nt], 0, 0, 0);
            }
            if (ks < 7) {
                unsigned short* bw = Bs + (buf ^ 1) * 5120 + srow * 40 + sch;
                *(uint4*)&bw[0] = n0;
                *(uint4*)&bw[8] = n1;
                __syncthreads();
            }
        }

        // ---- softmax over d (64 rows) -> qf fragment-major ----
#pragma unroll
        for (int nt = 0; nt < 8; nt++) {
#pragma unroll
            for (int r = 0; r < 4; r++) accq[nt][r] = __expf(accq[nt][r]);
            float s = accq[nt][0] + accq[nt][1] + accq[nt][2] + accq[nt][3];
            s += __shfl_xor(s, 16);
            s += __shfl_xor(s, 32);
            if (quad == 0) red[w * 128 + nt * 16 + l15] = s;
        }
        __syncthreads();                       // S2 (also drains buf1 reads)
        if (tid < 128) {
            float t = red[tid] + red[128 + tid] + red[256 + tid] + red[384 + tid];
            red[512 + tid] = 0.125f / t;
        }
        __syncthreads();                       // S3
#pragma unroll
        for (int nt = 0; nt < 8; nt++) {
            float li = red[512 + nt * 16 + l15];
            uint2 pp;
            pp.x = (unsigned int)f2bf(accq[nt][0] * li) |
                   ((unsigned int)f2bf(accq[nt][1] * li) << 16);
            pp.y = (unsigned int)f2bf(accq[nt][2] * li) |
                   ((unsigned int)f2bf(accq[nt][3] * li) << 16);
            *(uint2*)&Qs[(nt * 16 + l15) * 72 + w * 16 + quad * 4] = pp;
        }
        __syncthreads();                       // S4
        {
            // qf granule: ((((b*32+nbIdx)*16 + ks)*8 + nt)*64 + quad*16 + l15)
            const int n = tid >> 1, half = tid & 1;
            const int nbIdx = ch * 4 + st;
            const int ksq = h * 2 + half;
            const size_t gbase =
                (((size_t)(b * 32 + nbIdx) * 16 + ksq) * 8 + (n >> 4)) * 64 + (n & 15);
#pragma unroll
            for (int u = 0; u < 4; u++)
                *(uint4*)&qf[(gbase + u * 16) * 8] = *(uint4*)&Qs[n * 72 + half * 32 + u * 8];
        }
        __syncthreads();                       // S5: Qs/red dead before next Bs write
    }
}

// ---------------- K2b: k/v GEMM + exp(k) + phi ----------------
// grid (8 ch, 8 h, 16 b), block 256 (4 waves)
// LDS 32,768 B: Es[64][128] | Vs[64][128] ; Bs[2][128][40] ALIASES the
// Es/Vs region (live only during ks loop; Es/Vs live only from the
// post-ks deposit through the phi MFMA). Fences:
//   SA (st top)     : phi reads of st-1 done before Bs staging write
//   (in-loop dbuf barriers unchanged)
//   SB (post ks)    : last Bs MFMA reads done before Es/Vs deposits
//   S6 (post depos) : deposits visible before phi MFMA reads
// lb(256,2): 256-reg cap, compiles ~116 VGPR (R6-proven, no spill).
// Residency = min(LDS 160/32=5, VGPR 116<=128 -> 4, slots 8) = 4 blk/CU.
__global__ __launch_bounds__(256, 2) void kv_phi(
    const unsigned short* __restrict__ xT, const unsigned short* __restrict__ wf,
    float* __restrict__ phi, float* __restrict__ lsum)
{
    const int ch = blockIdx.x;
    const int h  = blockIdx.y;
    const int b  = blockIdx.z;
    const int tid  = threadIdx.x;
    const int lane = tid & 63;
    const int w    = tid >> 6;
    const int quad = lane >> 4;
    const int l15  = lane & 15;

    __shared__ unsigned short smem[16384];     // 32,768 B
    unsigned short* Es = smem;                 // [64][128]
    unsigned short* Vs = smem + 8192;          // [64][128]
    unsigned short* Bs = smem;                 // [2][128][40] (aliases Es/Vs)

    const unsigned short* wfk = wf + ((size_t)((1 * 8 + h) * 4 + w) * 8) * 512 + lane * 8;
    const unsigned short* wfv = wf + ((size_t)((2 * 8 + h) * 4 + w) * 8) * 512 + lane * 8;

    f32x4 pacc[4];
#pragma unroll
    for (int i = 0; i < 4; i++) pacc[i] = (f32x4)(0.f);
    float lacc[4] = {0.f, 0.f, 0.f, 0.f};

    const int srow = tid >> 1;
    const int sch  = (tid & 1) * 16;

    for (int st = 0; st < 4; st++) {
        const int nb = ch * 512 + st * 128;
        const unsigned short* xrow =
            xT + ((size_t)b * 4096 + nb + srow) * 256 + sch;

        f32x4 acck[8], accv[8];
#pragma unroll
        for (int i = 0; i < 8; i++) {
            acck[i] = (f32x4)(0.f); accv[i] = (f32x4)(0.f);
        }

        __syncthreads();                       // SA: phi reads (st-1) done
        {
            uint4 p0 = *(const uint4*)&xrow[0];
            uint4 p1 = *(const uint4*)&xrow[8];
            unsigned short* bw = Bs + srow * 40 + sch;
            *(uint4*)&bw[0] = p0;
            *(uint4*)&bw[8] = p1;
        }
        __syncthreads();

        for (int ks = 0; ks < 8; ks++) {
            const int buf = ks & 1;
            uint4 n0, n1;
            if (ks < 7) {
                n0 = *(const uint4*)&xrow[(ks + 1) * 32];
                n1 = *(const uint4*)&xrow[(ks + 1) * 32 + 8];
            }
            bf16x8 ak = *(const bf16x8*)&wfk[ks * 512];
            bf16x8 av = *(const bf16x8*)&wfv[ks * 512];
            const unsigned short* bsr = Bs + buf * 5120 + l15 * 40 + quad * 8;
#pragma unroll
            for (int nt = 0; nt < 8; nt++) {
                bf16x8 bv = *(const bf16x8*)&bsr[nt * 640];
                acck[nt] = __builtin_amdgcn_mfma_f32_16x16x32_bf16(ak, bv, acck[nt], 0, 0, 0);
                accv[nt] = __builtin_amdgcn_mfma_f32_16x16x32_bf16(av, bv, accv[nt], 0, 0, 0);
            }
            if (ks < 7) {
                unsigned short* bw = Bs + (buf ^ 1) * 5120 + srow * 40 + sch;
                *(uint4*)&bw[0] = n0;
                *(uint4*)&bw[8] = n1;
                __syncthreads();
            }
        }
        __syncthreads();                       // SB: Bs reads done

        // ---- k/v epilogue: exp, lsum partials, swizzled deposit ----
#pragma unroll
        for (int r = 0; r < 4; r++) {
            const int dl = quad * 4 + r;                            // d & 15
            const int dbase = (w * 16 + dl) * 256 + (l15 & 7) * 2;  // byte off
#pragma unroll
            for (int nt = 0; nt < 8; nt++) {
                const int pos = (2 * nt + (l15 >> 3)) ^ dl;
                float ek = __expf(acck[nt][r]);
                lacc[r] += ek;
                *(unsigned short*)((char*)Es + dbase + pos * 16) = f2bf(ek);
                *(unsigned short*)((char*)Vs + dbase + pos * 16) = f2bf(accv[nt][r]);
            }
        }
        __syncthreads();                       // S6

        // phi MFMA: phi[d][e] += sum_n expk[d][n] v[e][n], K=128
#pragma unroll
        for (int k2 = 0; k2 < 4; k2++) {
            bf16x8 ae = *(bf16x8*)((char*)Es + (w * 16 + l15) * 256 +
                                   (((k2 * 4 + quad) ^ l15) * 16));
#pragma unroll
            for (int et = 0; et < 4; et++) {
                bf16x8 bv = *(bf16x8*)((char*)Vs + (et * 16 + l15) * 256 +
                                       (((k2 * 4 + quad) ^ l15) * 16));
                pacc[et] = __builtin_amdgcn_mfma_f32_16x16x32_bf16(ae, bv, pacc[et], 0, 0, 0);
            }
        }
        // next st: SA fences Es/Vs reads before new Bs staging
    }

    // lsum: reduce over l15 then one atomic per d-row
#pragma unroll
    for (int r = 0; r < 4; r++) {
        float s = lacc[r];
        s += __shfl_xor(s, 1); s += __shfl_xor(s, 2);
        s += __shfl_xor(s, 4); s += __shfl_xor(s, 8);
        if (l15 == 0)
            atomicAdd(&lsum[((size_t)b * 8 + h) * 64 + w * 16 + quad * 4 + r], s);
    }
    float* pp = phi + ((size_t)b * 8 + h) * 4096;
#pragma unroll
    for (int et = 0; et < 4; et++)
#pragma unroll
        for (int r = 0; r < 4; r++)
            atomicAdd(&pp[(w * 16 + quad * 4 + r) * 64 + et * 16 + l15], pacc[et][r]);
}

// ---------------- K3: Mf = w_out · (phi/l), fragment-major bf16 ----------------
// grid (8 h, 16 b), block 256 (thread = c)
__global__ __launch_bounds__(256) void build_M(
    const float* __restrict__ phi, const float* __restrict__ lsum,
    const float* __restrict__ w_out, unsigned short* __restrict__ Mf)
{
    const int h = blockIdx.x, b = blockIdx.y;
    __shared__ float pT[64][68];  // [e][d]
    const float* pp = phi + ((size_t)b * 8 + h) * 4096;  // [d][e]
    const int tid = threadIdx.x;
    const int row = tid >> 2, ls = tid & 3;
#pragma unroll
    for (int u = 0; u < 4; u++) {
        int e0 = (ls + u * 4) * 4;
        float4 v = *(const float4*)&pp[row * 64 + e0];
        pT[e0 + 0][row] = v.x; pT[e0 + 1][row] = v.y;
        pT[e0 + 2][row] = v.z; pT[e0 + 3][row] = v.w;
    }
    __syncthreads();
    const int c = tid;
    float acc[64];
#pragma unroll
    for (int d = 0; d < 64; d++) acc[d] = 0.f;
    for (int e4 = 0; e4 < 16; e4++) {
        float4 wv = *(const float4*)&w_out[(size_t)c * 512 + h * 64 + e4 * 4];
        float wq[4] = {wv.x, wv.y, wv.z, wv.w};
#pragma unroll
        for (int qq = 0; qq < 4; qq++) {
            int e = e4 * 4 + qq;
#pragma unroll
            for (int d4 = 0; d4 < 16; d4++) {
                float4 p = *(const float4*)&pT[e][d4 * 4];
                acc[d4 * 4 + 0] += wq[qq] * p.x;
                acc[d4 * 4 + 1] += wq[qq] * p.y;
                acc[d4 * 4 + 2] += wq[qq] * p.z;
                acc[d4 * 4 + 3] += wq[qq] * p.w;
            }
        }
    }
    const float* lrow = lsum + ((size_t)b * 8 + h) * 64;
    unsigned short tmp[64];
#pragma unroll
    for (int d = 0; d < 64; d++) tmp[d] = f2bf(acc[d] / lrow[d]);
    // Mf granule: ((((b*2+ct)*2+wr)*4+mi)*16 + ks)*64 + quad*16 + l15c
    const int ct = c >> 7, wr = (c >> 6) & 1, mi = (c >> 4) & 3, l15c = c & 15;
#pragma unroll
    for (int u = 0; u < 8; u++) {
        const int ksA = h * 2 + (u >> 2);
        const int quadA = u & 3;
        size_t gidx = ((((size_t)(b * 2 + ct) * 2 + wr) * 4 + mi) * 16 + ksA) * 64
                      + quadA * 16 + l15c;
        *(uint4*)&Mf[gidx * 8] = *(uint4*)&tmp[u * 8];
    }
}

// ---------------- K4: out = M · q, LDS-free, all-coalesced ----------------
// grid (32 nblocks, 2 ctiles, 16 b), block 256 (4 waves, 2x2)
__global__ __launch_bounds__(256, 3) void out_mfma(
    const unsigned short* __restrict__ Mf, const unsigned short* __restrict__ qf,
    float* __restrict__ out)
{
    const int nbIdx = blockIdx.x;
    const int ct    = blockIdx.y;
    const int b     = blockIdx.z;
    const int tid  = threadIdx.x;
    const int lane = tid & 63;
    const int w    = tid >> 6;
    const int wr   = w >> 1, wc = w & 1;
    const int quad = lane >> 4;
    const int l15  = lane & 15;

    f32x4 acc[4][4];
#pragma unroll
    for (int i = 0; i < 4; i++)
#pragma unroll
        for (int j = 0; j < 4; j++) acc[i][j] = (f32x4)(0.f);

    const unsigned short* Ab =
        Mf + ((((size_t)(b * 2 + ct) * 2 + wr) * 4) * 16) * 512 + lane * 8;
    const unsigned short* Bb =
        qf + (((size_t)(b * 32 + nbIdx) * 16) * 8) * 512 + lane * 8;

    for (int ks = 0; ks < 16; ks++) {
        bf16x8 af[4], bv[4];
#pragma unroll
        for (int mi = 0; mi < 4; mi++)
            af[mi] = *(const bf16x8*)&Ab[(size_t)(mi * 16 + ks) * 512];
#pragma unroll
        for (int ni = 0; ni < 4; ni++)
            bv[ni] = *(const bf16x8*)&Bb[(size_t)(ks * 8 + wc * 4 + ni) * 512];
#pragma unroll
        for (int mi = 0; mi < 4; mi++)
#pragma unroll
            for (int ni = 0; ni < 4; ni++)
                acc[mi][ni] = __builtin_amdgcn_mfma_f32_16x16x32_bf16(
                    af[mi], bv[ni], acc[mi][ni], 0, 0, 0);
    }
    float* ob = out + ((size_t)b * 256 + ct * 128 + wr * 64) * 4096
                + nbIdx * 128 + wc * 64;
#pragma unroll
    for (int mi = 0; mi < 4; mi++)
#pragma unroll
        for (int ni = 0; ni < 4; ni++)
#pragma unroll
            for (int r = 0; r < 4; r++)
                ob[(size_t)(mi * 16 + quad * 4 + r) * 4096 + ni * 16 + l15]
                    = acc[mi][ni][r];
}

extern "C" void kernel_launch(void* const* d_in, const int* in_sizes, int n_in,
                              void* d_out, int out_size, void* d_ws, size_t ws_size,
                              hipStream_t stream) {
    const float* x     = (const float*)d_in[0];
    const float* w_qkv = (const float*)d_in[1];
    const float* w_out = (const float*)d_in[2];
    float* out = (float*)d_out;

    char* ws = (char*)d_ws;
    unsigned short* qf = (unsigned short*)ws;                     // 67,108,864 B
    unsigned short* wf = (unsigned short*)(ws + 67108864);        //    786,432 B
    float* lsum = (float*)(ws + 67895296);                        //     32,768 B
    float* phi  = (float*)(ws + 67928064);                        //  2,097,152 B
    unsigned short* Mf = (unsigned short*)(ws + 70025216);        //  4,194,304 B
    unsigned short* xT = (unsigned short*)(ws + 74219520);        // 33,554,432 B
    // total ws: 107,773,952 B (same as R6, proven safe)

    hipMemsetAsync(lsum, 0, (8192 + 524288) * sizeof(float), stream);

    cvt_w_frag<<<192, 256, 0, stream>>>(w_qkv, wf);
    cvt_xT<<<dim3(64, 4, 16), 256, 0, stream>>>(x, xT);
    q_gemm<<<dim3(8, 8, 16), 256, 0, stream>>>(xT, wf, qf);
    kv_phi<<<dim3(8, 8, 16), 256, 0, stream>>>(xT, wf, phi, lsum);
    build_M<<<dim3(8, 16), 256, 0, stream>>>(phi, lsum, w_out, Mf);
    out_mfma<<<dim3(32, 2, 16), 256, 0, stream>>>(Mf, qf, out);
}

// Round 4
// 277.497 us; speedup vs baseline: 1.2674x; 1.0123x over previous
//
#include <hip/hip_runtime.h>
#include <hip/hip_bf16.h>

// LinearAttention MI355X: B=16, C=256, n=4096, h=8, d=64, SCALE=0.125
// R9: BK=64 phase-merge in q_gemm/kv_phi. R8 showed latency/sync-bound
//   (MfmaUtil 22, VALU 17, HBM 3%, occupancy insensitive to LDS): the
//   2-phase ks loop pays a full vmcnt-drain+barrier per 16 MFMA. Now 32
//   MFMA per barrier; in-loop barriers 7->3 per st (44->28 per block).
//   Bs[2][128][72] (64 ch + 8 pad), 36,864 B. q_gemm: red aliases buf0,
//   Qs aliases buf1 (exactly); S5 dropped (post-prologue barrier fences
//   ks=0 buf1 prefetch vs Qs reads). Launch bounds loose (R7 lesson).
//   K0 cvt_w_frag: w_qkv -> wf fragment-major [op][h][w][ks][lane][8]
//   K1 cvt_xT    : xT[b][n][c] = bf16(x[b][c][n])
//   K2a q_gemm   : q GEMM + softmax(d) -> qf fragment-major
//   K2b kv_phi   : k/v GEMM + exp(k) -> swizzled LDS -> phi MFMA; atomics
//   K3 build_M   : Mf (fragment-major) = bf16(w_out · phi / lsum)
//   K4 out_mfma  : out = M · q, LDS-free, all-coalesced fragment loads
// ws layout unchanged from R6.

typedef __attribute__((ext_vector_type(8))) short bf16x8;
typedef __attribute__((ext_vector_type(4))) float f32x4;

__device__ __forceinline__ unsigned short f2bf(float f) {
    union { float f; unsigned int i; } w; w.f = f;
    unsigned int r = w.i + 0x7FFFu + ((w.i >> 16) & 1u);
    return (unsigned short)(r >> 16);
}

// ---------------- K0: w_qkv -> fragment-major bf16 ----------------
// granule g: lane=g&63, ks=(g>>6)&7, w2=(g>>9)&3, h=(g>>11)&7, op=g>>14
__global__ __launch_bounds__(256) void cvt_w_frag(
    const float* __restrict__ wqkv, unsigned short* __restrict__ wf)
{
    int g = blockIdx.x * 256 + threadIdx.x;    // 49152 granules, grid 192
    int lane = g & 63;
    int ks   = (g >> 6) & 7;
    int w2   = (g >> 9) & 3;
    int h    = (g >> 11) & 7;
    int op   = g >> 14;
    int row = op * 512 + h * 64 + w2 * 16 + (lane & 15);
    int col = ks * 32 + (lane >> 4) * 8;
    const float* src = &wqkv[(size_t)row * 256 + col];
    float4 f0 = *(const float4*)&src[0];
    float4 f1 = *(const float4*)&src[4];
    unsigned short t[8] = {f2bf(f0.x), f2bf(f0.y), f2bf(f0.z), f2bf(f0.w),
                           f2bf(f1.x), f2bf(f1.y), f2bf(f1.z), f2bf(f1.w)};
    *(uint4*)&wf[(size_t)g * 8] = *(uint4*)t;
}

// ---------------- K1: x[b][c][n] f32 -> xT[b][n][c] bf16 ----------------
__global__ __launch_bounds__(256) void cvt_xT(
    const float* __restrict__ x, unsigned short* __restrict__ xT)
{
    const int nb = blockIdx.x * 64, cb = blockIdx.y * 64, b = blockIdx.z;
    __shared__ float Ts[64 * 65];
    const int tid = threadIdx.x;
    const int l = tid & 63, w = tid >> 6;
    const float* xb = x + ((size_t)b * 256 + cb) * 4096 + nb;
#pragma unroll
    for (int p = 0; p < 4; p++) {
        int c = p * 16 + (tid >> 4);
        int n4 = (tid & 15) * 4;
        float4 v = *(const float4*)&xb[(size_t)c * 4096 + n4];
        Ts[c * 65 + n4 + 0] = v.x; Ts[c * 65 + n4 + 1] = v.y;
        Ts[c * 65 + n4 + 2] = v.z; Ts[c * 65 + n4 + 3] = v.w;
    }
    __syncthreads();
    unsigned short t[16];
#pragma unroll
    for (int i = 0; i < 16; i++) t[i] = f2bf(Ts[(w * 16 + i) * 65 + l]);
    unsigned short* dst = xT + ((size_t)b * 4096 + nb + l) * 256 + cb + w * 16;
    *(uint4*)&dst[0] = *(uint4*)&t[0];
    *(uint4*)&dst[8] = *(uint4*)&t[8];
}

// ---------------- K2a: q GEMM + softmax(d) -> qf ----------------
// grid (8 ch, 8 h, 16 b), block 256 (4 waves), BK=64
// LDS 36,864 B: Bs[2][128][72]. red (640 f32) aliases buf0 (dead: last
// buf0 MFMA reads drained at ks=2 barrier). Qs[128][72] aliases buf1
// exactly (written after S3; buf1 reads drained at S2; next-st ks=0
// prefetch into buf1 is after post-prologue barrier, which drains the
// Qs reads of the qf store).
__global__ __launch_bounds__(256, 3) void q_gemm(
    const unsigned short* __restrict__ xT, const unsigned short* __restrict__ wf,
    unsigned short* __restrict__ qf)
{
    const int ch = blockIdx.x;
    const int h  = blockIdx.y;
    const int b  = blockIdx.z;
    const int tid  = threadIdx.x;
    const int lane = tid & 63;
    const int w    = tid >> 6;
    const int quad = lane >> 4;
    const int l15  = lane & 15;

    __shared__ unsigned short smem[18432];     // 36,864 B
    unsigned short* Bs = smem;                 // [2][128][72]
    float* red = (float*)smem;                 // 640 f32 (aliases buf0)
    unsigned short* Qs = smem + 9216;          // [128][72] (aliases buf1)

    const unsigned short* wfq = wf + ((size_t)((0 * 8 + h) * 4 + w) * 8) * 512 + lane * 8;

    const int srow = tid >> 1;                 // staging row 0..127
    const int sch  = (tid & 1) * 32;           // 0/32 shorts (64 B per thread)

    for (int st = 0; st < 4; st++) {
        const int nb = ch * 512 + st * 128;
        const unsigned short* xrow =
            xT + ((size_t)b * 4096 + nb + srow) * 256 + sch;

        f32x4 accq[8];
#pragma unroll
        for (int i = 0; i < 8; i++) accq[i] = (f32x4)(0.f);

        {   // prologue: stage ks=0 (64 ch) into buf 0
            uint4 p0 = *(const uint4*)&xrow[0];
            uint4 p1 = *(const uint4*)&xrow[8];
            uint4 p2 = *(const uint4*)&xrow[16];
            uint4 p3 = *(const uint4*)&xrow[24];
            unsigned short* bw = Bs + srow * 72 + sch;
            *(uint4*)&bw[0]  = p0; *(uint4*)&bw[8]  = p1;
            *(uint4*)&bw[16] = p2; *(uint4*)&bw[24] = p3;
        }
        __syncthreads();

        for (int ks = 0; ks < 4; ks++) {
            const int buf = ks & 1;
            uint4 n0, n1, n2, n3;
            if (ks < 3) {
                n0 = *(const uint4*)&xrow[(ks + 1) * 64];
                n1 = *(const uint4*)&xrow[(ks + 1) * 64 + 8];
                n2 = *(const uint4*)&xrow[(ks + 1) * 64 + 16];
                n3 = *(const uint4*)&xrow[(ks + 1) * 64 + 24];
            }
            bf16x8 aq0 = *(const bf16x8*)&wfq[(2 * ks) * 512];
            bf16x8 aq1 = *(const bf16x8*)&wfq[(2 * ks + 1) * 512];
            const unsigned short* bsr = Bs + buf * 9216 + l15 * 72 + quad * 8;
#pragma unroll
            for (int nt = 0; nt < 8; nt++) {
                bf16x8 bv0 = *(const bf16x8*)&bsr[nt * 1152];        // 16 rows * 72
                bf16x8 bv1 = *(const bf16x8*)&bsr[nt * 1152 + 32];
                accq[nt] = __builtin_amdgcn_mfma_f32_16x16x32_bf16(aq0, bv0, accq[nt], 0, 0, 0);
                accq[nt] = __builtin_amdgcn_mfma_f32_16x16x32_bf16(aq1, bv1, accq[nt], 0, 0, 0);
            }
            if (ks < 3) {
                unsigned short* bw = Bs + (buf ^ 1) * 9216 + srow * 72 + sch;
                *(uint4*)&bw[0]  = n0; *(uint4*)&bw[8]  = n1;
                *(uint4*)&bw[16] = n2; *(uint4*)&bw[24] = n3;
                __syncthreads();
            }
        }

        // ---- softmax over d (64 rows) -> qf fragment-major ----
#pragma unroll
        for (int nt = 0; nt < 8; nt++) {
#pragma unroll
            for (int r = 0; r < 4; r++) accq[nt][r] = __expf(accq[nt][r]);
            float s = accq[nt][0] + accq[nt][1] + accq[nt][2] + accq[nt][3];
            s += __shfl_xor(s, 16);
            s += __shfl_xor(s, 32);
            if (quad == 0) red[w * 128 + nt * 16 + l15] = s;
        }
        __syncthreads();                       // S2 (drains buf1 MFMA reads)
        if (tid < 128) {
            float t = red[tid] + red[128 + tid] + red[256 + tid] + red[384 + tid];
            red[512 + tid] = 0.125f / t;
        }
        __syncthreads();                       // S3
#pragma unroll
        for (int nt = 0; nt < 8; nt++) {
            float li = red[512 + nt * 16 + l15];
            uint2 pp;
            pp.x = (unsigned int)f2bf(accq[nt][0] * li) |
                   ((unsigned int)f2bf(accq[nt][1] * li) << 16);
            pp.y = (unsigned int)f2bf(accq[nt][2] * li) |
                   ((unsigned int)f2bf(accq[nt][3] * li) << 16);
            *(uint2*)&Qs[(nt * 16 + l15) * 72 + w * 16 + quad * 4] = pp;
        }
        __syncthreads();                       // S4
        {
            // qf granule: ((((b*32+nbIdx)*16 + ks)*8 + nt)*64 + quad*16 + l15)
            const int n = tid >> 1, half = tid & 1;
            const int nbIdx = ch * 4 + st;
            const int ksq = h * 2 + half;
            const size_t gbase =
                (((size_t)(b * 32 + nbIdx) * 16 + ksq) * 8 + (n >> 4)) * 64 + (n & 15);
#pragma unroll
            for (int u = 0; u < 4; u++)
                *(uint4*)&qf[(gbase + u * 16) * 8] = *(uint4*)&Qs[n * 72 + half * 32 + u * 8];
        }
        // next st: prologue writes buf0 (disjoint from Qs=buf1; red reads
        // were drained at S4); ks=0 prefetch into buf1 is after the
        // post-prologue barrier, which drains this st's Qs reads.
    }
}

// ---------------- K2b: k/v GEMM + exp(k) + phi ----------------
// grid (8 ch, 8 h, 16 b), block 256 (4 waves), BK=64
// LDS 36,864 B: Bs[2][128][72]; Es[64][128]|Vs[64][128] (32,768 B)
// alias the Bs region (live only deposit->phi MFMA). Fences:
//   SA (st top)     : phi reads of st-1 done before Bs staging write
//   post-prologue + 3 in-loop dbuf barriers
//   SB (post ks)    : last Bs MFMA reads done before Es/Vs deposits
//   S6 (post depos) : deposits visible before phi MFMA reads
__global__ __launch_bounds__(256, 2) void kv_phi(
    const unsigned short* __restrict__ xT, const unsigned short* __restrict__ wf,
    float* __restrict__ phi, float* __restrict__ lsum)
{
    const int ch = blockIdx.x;
    const int h  = blockIdx.y;
    const int b  = blockIdx.z;
    const int tid  = threadIdx.x;
    const int lane = tid & 63;
    const int w    = tid >> 6;
    const int quad = lane >> 4;
    const int l15  = lane & 15;

    __shared__ unsigned short smem[18432];     // 36,864 B
    unsigned short* Es = smem;                 // [64][128]
    unsigned short* Vs = smem + 8192;          // [64][128]
    unsigned short* Bs = smem;                 // [2][128][72] (aliases Es/Vs)

    const unsigned short* wfk = wf + ((size_t)((1 * 8 + h) * 4 + w) * 8) * 512 + lane * 8;
    const unsigned short* wfv = wf + ((size_t)((2 * 8 + h) * 4 + w) * 8) * 512 + lane * 8;

    f32x4 pacc[4];
#pragma unroll
    for (int i = 0; i < 4; i++) pacc[i] = (f32x4)(0.f);
    float lacc[4] = {0.f, 0.f, 0.f, 0.f};

    const int srow = tid >> 1;
    const int sch  = (tid & 1) * 32;           // 0/32 shorts (64 B per thread)

    for (int st = 0; st < 4; st++) {
        const int nb = ch * 512 + st * 128;
        const unsigned short* xrow =
            xT + ((size_t)b * 4096 + nb + srow) * 256 + sch;

        f32x4 acck[8], accv[8];
#pragma unroll
        for (int i = 0; i < 8; i++) {
            acck[i] = (f32x4)(0.f); accv[i] = (f32x4)(0.f);
        }

        __syncthreads();                       // SA: phi reads (st-1) done
        {   // prologue: stage ks=0 (64 ch) into buf 0
            uint4 p0 = *(const uint4*)&xrow[0];
            uint4 p1 = *(const uint4*)&xrow[8];
            uint4 p2 = *(const uint4*)&xrow[16];
            uint4 p3 = *(const uint4*)&xrow[24];
            unsigned short* bw = Bs + srow * 72 + sch;
            *(uint4*)&bw[0]  = p0; *(uint4*)&bw[8]  = p1;
            *(uint4*)&bw[16] = p2; *(uint4*)&bw[24] = p3;
        }
        __syncthreads();

        for (int ks = 0; ks < 4; ks++) {
            const int buf = ks & 1;
            uint4 n0, n1, n2, n3;
            if (ks < 3) {
                n0 = *(const uint4*)&xrow[(ks + 1) * 64];
                n1 = *(const uint4*)&xrow[(ks + 1) * 64 + 8];
                n2 = *(const uint4*)&xrow[(ks + 1) * 64 + 16];
                n3 = *(const uint4*)&xrow[(ks + 1) * 64 + 24];
            }
            bf16x8 ak0 = *(const bf16x8*)&wfk[(2 * ks) * 512];
            bf16x8 ak1 = *(const bf16x8*)&wfk[(2 * ks + 1) * 512];
            bf16x8 av0 = *(const bf16x8*)&wfv[(2 * ks) * 512];
            bf16x8 av1 = *(const bf16x8*)&wfv[(2 * ks + 1) * 512];
            const unsigned short* bsr = Bs + buf * 9216 + l15 * 72 + quad * 8;
#pragma unroll
            for (int nt = 0; nt < 8; nt++) {
                bf16x8 bv0 = *(const bf16x8*)&bsr[nt * 1152];
                bf16x8 bv1 = *(const bf16x8*)&bsr[nt * 1152 + 32];
                acck[nt] = __builtin_amdgcn_mfma_f32_16x16x32_bf16(ak0, bv0, acck[nt], 0, 0, 0);
                accv[nt] = __builtin_amdgcn_mfma_f32_16x16x32_bf16(av0, bv0, accv[nt], 0, 0, 0);
                acck[nt] = __builtin_amdgcn_mfma_f32_16x16x32_bf16(ak1, bv1, acck[nt], 0, 0, 0);
                accv[nt] = __builtin_amdgcn_mfma_f32_16x16x32_bf16(av1, bv1, accv[nt], 0, 0, 0);
            }
            if (ks < 3) {
                unsigned short* bw = Bs + (buf ^ 1) * 9216 + srow * 72 + sch;
                *(uint4*)&bw[0]  = n0; *(uint4*)&bw[8]  = n1;
                *(uint4*)&bw[16] = n2; *(uint4*)&bw[24] = n3;
                __syncthreads();
            }
        }
        __syncthreads();                       // SB: Bs reads done

        // ---- k/v epilogue: exp, lsum partials, swizzled deposit ----
#pragma unroll
        for (int r = 0; r < 4; r++) {
            const int dl = quad * 4 + r;                            // d & 15
            const int dbase = (w * 16 + dl) * 256 + (l15 & 7) * 2;  // byte off
#pragma unroll
            for (int nt = 0; nt < 8; nt++) {
                const int pos = (2 * nt + (l15 >> 3)) ^ dl;
                float ek = __expf(acck[nt][r]);
                lacc[r] += ek;
                *(unsigned short*)((char*)Es + dbase + pos * 16) = f2bf(ek);
                *(unsigned short*)((char*)Vs + dbase + pos * 16) = f2bf(accv[nt][r]);
            }
        }
        __syncthreads();                       // S6

        // phi MFMA: phi[d][e] += sum_n expk[d][n] v[e][n], K=128
#pragma unroll
        for (int k2 = 0; k2 < 4; k2++) {
            bf16x8 ae = *(bf16x8*)((char*)Es + (w * 16 + l15) * 256 +
                                   (((k2 * 4 + quad) ^ l15) * 16));
#pragma unroll
            for (int et = 0; et < 4; et++) {
                bf16x8 bv = *(bf16x8*)((char*)Vs + (et * 16 + l15) * 256 +
                                       (((k2 * 4 + quad) ^ l15) * 16));
                pacc[et] = __builtin_amdgcn_mfma_f32_16x16x32_bf16(ae, bv, pacc[et], 0, 0, 0);
            }
        }
        // next st: SA fences Es/Vs reads before new Bs staging
    }

    // lsum: reduce over l15 then one atomic per d-row
#pragma unroll
    for (int r = 0; r < 4; r++) {
        float s = lacc[r];
        s += __shfl_xor(s, 1); s += __shfl_xor(s, 2);
        s += __shfl_xor(s, 4); s += __shfl_xor(s, 8);
        if (l15 == 0)
            atomicAdd(&lsum[((size_t)b * 8 + h) * 64 + w * 16 + quad * 4 + r], s);
    }
    float* pp = phi + ((size_t)b * 8 + h) * 4096;
#pragma unroll
    for (int et = 0; et < 4; et++)
#pragma unroll
        for (int r = 0; r < 4; r++)
            atomicAdd(&pp[(w * 16 + quad * 4 + r) * 64 + et * 16 + l15], pacc[et][r]);
}

// ---------------- K3: Mf = w_out · (phi/l), fragment-major bf16 ----------------
// grid (8 h, 16 b), block 256 (thread = c)
__global__ __launch_bounds__(256) void build_M(
    const float* __restrict__ phi, const float* __restrict__ lsum,
    const float* __restrict__ w_out, unsigned short* __restrict__ Mf)
{
    const int h = blockIdx.x, b = blockIdx.y;
    __shared__ float pT[64][68];  // [e][d]
    const float* pp = phi + ((size_t)b * 8 + h) * 4096;  // [d][e]
    const int tid = threadIdx.x;
    const int row = tid >> 2, ls = tid & 3;
#pragma unroll
    for (int u = 0; u < 4; u++) {
        int e0 = (ls + u * 4) * 4;
        float4 v = *(const float4*)&pp[row * 64 + e0];
        pT[e0 + 0][row] = v.x; pT[e0 + 1][row] = v.y;
        pT[e0 + 2][row] = v.z; pT[e0 + 3][row] = v.w;
    }
    __syncthreads();
    const int c = tid;
    float acc[64];
#pragma unroll
    for (int d = 0; d < 64; d++) acc[d] = 0.f;
    for (int e4 = 0; e4 < 16; e4++) {
        float4 wv = *(const float4*)&w_out[(size_t)c * 512 + h * 64 + e4 * 4];
        float wq[4] = {wv.x, wv.y, wv.z, wv.w};
#pragma unroll
        for (int qq = 0; qq < 4; qq++) {
            int e = e4 * 4 + qq;
#pragma unroll
            for (int d4 = 0; d4 < 16; d4++) {
                float4 p = *(const float4*)&pT[e][d4 * 4];
                acc[d4 * 4 + 0] += wq[qq] * p.x;
                acc[d4 * 4 + 1] += wq[qq] * p.y;
                acc[d4 * 4 + 2] += wq[qq] * p.z;
                acc[d4 * 4 + 3] += wq[qq] * p.w;
            }
        }
    }
    const float* lrow = lsum + ((size_t)b * 8 + h) * 64;
    unsigned short tmp[64];
#pragma unroll
    for (int d = 0; d < 64; d++) tmp[d] = f2bf(acc[d] / lrow[d]);
    // Mf granule: ((((b*2+ct)*2+wr)*4+mi)*16 + ks)*64 + quad*16 + l15c
    const int ct = c >> 7, wr = (c >> 6) & 1, mi = (c >> 4) & 3, l15c = c & 15;
#pragma unroll
    for (int u = 0; u < 8; u++) {
        const int ksA = h * 2 + (u >> 2);
        const int quadA = u & 3;
        size_t gidx = ((((size_t)(b * 2 + ct) * 2 + wr) * 4 + mi) * 16 + ksA) * 64
                      + quadA * 16 + l15c;
        *(uint4*)&Mf[gidx * 8] = *(uint4*)&tmp[u * 8];
    }
}

// ---------------- K4: out = M · q, LDS-free, all-coalesced ----------------
// grid (32 nblocks, 2 ctiles, 16 b), block 256 (4 waves, 2x2)
__global__ __launch_bounds__(256, 3) void out_mfma(
    const unsigned short* __restrict__ Mf, const unsigned short* __restrict__ qf,
    float* __restrict__ out)
{
    const int nbIdx = blockIdx.x;
    const int ct    = blockIdx.y;
    const int b     = blockIdx.z;
    const int tid  = threadIdx.x;
    const int lane = tid & 63;
    const int w    = tid >> 6;
    const int wr   = w >> 1, wc = w & 1;
    const int quad = lane >> 4;
    const int l15  = lane & 15;

    f32x4 acc[4][4];
#pragma unroll
    for (int i = 0; i < 4; i++)
#pragma unroll
        for (int j = 0; j < 4; j++) acc[i][j] = (f32x4)(0.f);

    const unsigned short* Ab =
        Mf + ((((size_t)(b * 2 + ct) * 2 + wr) * 4) * 16) * 512 + lane * 8;
    const unsigned short* Bb =
        qf + (((size_t)(b * 32 + nbIdx) * 16) * 8) * 512 + lane * 8;

    for (int ks = 0; ks < 16; ks++) {
        bf16x8 af[4], bv[4];
#pragma unroll
        for (int mi = 0; mi < 4; mi++)
            af[mi] = *(const bf16x8*)&Ab[(size_t)(mi * 16 + ks) * 512];
#pragma unroll
        for (int ni = 0; ni < 4; ni++)
            bv[ni] = *(const bf16x8*)&Bb[(size_t)(ks * 8 + wc * 4 + ni) * 512];
#pragma unroll
        for (int mi = 0; mi < 4; mi++)
#pragma unroll
            for (int ni = 0; ni < 4; ni++)
                acc[mi][ni] = __builtin_amdgcn_mfma_f32_16x16x32_bf16(
                    af[mi], bv[ni], acc[mi][ni], 0, 0, 0);
    }
    float* ob = out + ((size_t)b * 256 + ct * 128 + wr * 64) * 4096
                + nbIdx * 128 + wc * 64;
#pragma unroll
    for (int mi = 0; mi < 4; mi++)
#pragma unroll
        for (int ni = 0; ni < 4; ni++)
#pragma unroll
            for (int r = 0; r < 4; r++)
                ob[(size_t)(mi * 16 + quad * 4 + r) * 4096 + ni * 16 + l15]
                    = acc[mi][ni][r];
}

extern "C" void kernel_launch(void* const* d_in, const int* in_sizes, int n_in,
                              void* d_out, int out_size, void* d_ws, size_t ws_size,
                              hipStream_t stream) {
    const float* x     = (const float*)d_in[0];
    const float* w_qkv = (const float*)d_in[1];
    const float* w_out = (const float*)d_in[2];
    float* out = (float*)d_out;

    char* ws = (char*)d_ws;
    unsigned short* qf = (unsigned short*)ws;                     // 67,108,864 B
    unsigned short* wf = (unsigned short*)(ws + 67108864);        //    786,432 B
    float* lsum = (float*)(ws + 67895296);                        //     32,768 B
    float* phi  = (float*)(ws + 67928064);                        //  2,097,152 B
    unsigned short* Mf = (unsigned short*)(ws + 70025216);        //  4,194,304 B
    unsigned short* xT = (unsigned short*)(ws + 74219520);        // 33,554,432 B
    // total ws: 107,773,952 B (same as R6, proven safe)

    hipMemsetAsync(lsum, 0, (8192 + 524288) * sizeof(float), stream);

    cvt_w_frag<<<192, 256, 0, stream>>>(w_qkv, wf);
    cvt_xT<<<dim3(64, 4, 16), 256, 0, stream>>>(x, xT);
    q_gemm<<<dim3(8, 8, 16), 256, 0, stream>>>(xT, wf, qf);
    kv_phi<<<dim3(8, 8, 16), 256, 0, stream>>>(xT, wf, phi, lsum);
    build_M<<<dim3(8, 16), 256, 0, stream>>>(phi, lsum, w_out, Mf);
    out_mfma<<<dim3(32, 2, 16), 256, 0, stream>>>(Mf, qf, out);
}

// Round 5
// 262.865 us; speedup vs baseline: 1.3380x; 1.0557x over previous
//
#include <hip/hip_runtime.h>
#include <hip/hip_bf16.h>

// LinearAttention MI355X: B=16, C=256, n=4096, h=8, d=64, SCALE=0.125
// R10: staging via global_load_lds(16B) in q_gemm/kv_phi (R9 showed
//   barrier count is not the constraint; reg-staged copies are —
//   Common-mistake #1: gload_lds removes 4 global loads + 4 ds_writes +
//   prefetch regs + addr VALU per phase). Bs now LINEAR [2][128][64]
//   (32 KB exactly, pad dropped); bank conflicts fixed by XOR swizzle
//   done both-sides (rule #21): per-lane pre-swizzled global SOURCE
//   (chunk (l&7)^(l>>3)) + same XOR on the ds_read side
//   (chunk quad^(l15&7)) -> 2-way (free). q_gemm: A-frags hoisted
//   (st-invariant, static-indexed), Qs(18KB,stride 72) = buf1 + buf0
//   tail, S5 restored. kv_phi: Es/Vs alias Bs (SA/SB/S6 fences kept);
//   gload queue drained 1 phase before any aliased overwrite.
//   K0 cvt_w_frag: w_qkv -> wf fragment-major [op][h][w][ks][lane][8]
//   K1 cvt_xT    : xT[b][n][c] = bf16(x[b][c][n])
//   K2a q_gemm   : q GEMM + softmax(d) -> qf fragment-major
//   K2b kv_phi   : k/v GEMM + exp(k) -> swizzled LDS -> phi MFMA; atomics
//   K3 build_M   : Mf (fragment-major) = bf16(w_out · phi / lsum)
//   K4 out_mfma  : out = M · q, LDS-free, all-coalesced fragment loads
// ws layout unchanged from R6.

typedef __attribute__((ext_vector_type(8))) short bf16x8;
typedef __attribute__((ext_vector_type(4))) float f32x4;

__device__ __forceinline__ unsigned short f2bf(float f) {
    union { float f; unsigned int i; } w; w.f = f;
    unsigned int r = w.i + 0x7FFFu + ((w.i >> 16) & 1u);
    return (unsigned short)(r >> 16);
}

// async global->LDS, 16B per lane; LDS dest = uniform base + lane*16
__device__ __forceinline__ void gload16(const unsigned short* g, unsigned short* l) {
    __builtin_amdgcn_global_load_lds(
        (const __attribute__((address_space(1))) void*)(const void*)g,
        (__attribute__((address_space(3))) void*)(void*)l,
        16, 0, 0);
}

// ---------------- K0: w_qkv -> fragment-major bf16 ----------------
// granule g: lane=g&63, ks=(g>>6)&7, w2=(g>>9)&3, h=(g>>11)&7, op=g>>14
__global__ __launch_bounds__(256) void cvt_w_frag(
    const float* __restrict__ wqkv, unsigned short* __restrict__ wf)
{
    int g = blockIdx.x * 256 + threadIdx.x;    // 49152 granules, grid 192
    int lane = g & 63;
    int ks   = (g >> 6) & 7;
    int w2   = (g >> 9) & 3;
    int h    = (g >> 11) & 7;
    int op   = g >> 14;
    int row = op * 512 + h * 64 + w2 * 16 + (lane & 15);
    int col = ks * 32 + (lane >> 4) * 8;
    const float* src = &wqkv[(size_t)row * 256 + col];
    float4 f0 = *(const float4*)&src[0];
    float4 f1 = *(const float4*)&src[4];
    unsigned short t[8] = {f2bf(f0.x), f2bf(f0.y), f2bf(f0.z), f2bf(f0.w),
                           f2bf(f1.x), f2bf(f1.y), f2bf(f1.z), f2bf(f1.w)};
    *(uint4*)&wf[(size_t)g * 8] = *(uint4*)t;
}

// ---------------- K1: x[b][c][n] f32 -> xT[b][n][c] bf16 ----------------
__global__ __launch_bounds__(256) void cvt_xT(
    const float* __restrict__ x, unsigned short* __restrict__ xT)
{
    const int nb = blockIdx.x * 64, cb = blockIdx.y * 64, b = blockIdx.z;
    __shared__ float Ts[64 * 65];
    const int tid = threadIdx.x;
    const int l = tid & 63, w = tid >> 6;
    const float* xb = x + ((size_t)b * 256 + cb) * 4096 + nb;
#pragma unroll
    for (int p = 0; p < 4; p++) {
        int c = p * 16 + (tid >> 4);
        int n4 = (tid & 15) * 4;
        float4 v = *(const float4*)&xb[(size_t)c * 4096 + n4];
        Ts[c * 65 + n4 + 0] = v.x; Ts[c * 65 + n4 + 1] = v.y;
        Ts[c * 65 + n4 + 2] = v.z; Ts[c * 65 + n4 + 3] = v.w;
    }
    __syncthreads();
    unsigned short t[16];
#pragma unroll
    for (int i = 0; i < 16; i++) t[i] = f2bf(Ts[(w * 16 + i) * 65 + l]);
    unsigned short* dst = xT + ((size_t)b * 4096 + nb + l) * 256 + cb + w * 16;
    *(uint4*)&dst[0] = *(uint4*)&t[0];
    *(uint4*)&dst[8] = *(uint4*)&t[8];
}

// ---------------- K2a: q GEMM + softmax(d) -> qf ----------------
// grid (8 ch, 8 h, 16 b), block 256 (4 waves), BK=64
// LDS 32,768 B: Bs[2][128][64] linear (gload_lds dest). red (640 f32)
// at buf0 head (buf0 last MFMA-read at ks=2, drained at ks=2 barrier).
// Qs[128][72] at byte 14336 = buf0 tail (rows 112-127) + buf1; written
// after S3 (both bufs dead), read before S5; S5 fences next-st staging.
__global__ __launch_bounds__(256, 3) void q_gemm(
    const unsigned short* __restrict__ xT, const unsigned short* __restrict__ wf,
    unsigned short* __restrict__ qf)
{
    const int ch = blockIdx.x;
    const int h  = blockIdx.y;
    const int b  = blockIdx.z;
    const int tid  = threadIdx.x;
    const int lane = tid & 63;
    const int w    = tid >> 6;
    const int quad = lane >> 4;
    const int l15  = lane & 15;

    __shared__ unsigned short smem[16384];     // 32,768 B
    unsigned short* Bs = smem;                 // [2][128][64] linear
    float* red = (float*)smem;                 // 640 f32 (buf0 head)
    unsigned short* Qs = smem + 7168;          // [128][72] (buf0 tail+buf1)

    const unsigned short* wfq = wf + ((size_t)((0 * 8 + h) * 4 + w) * 8) * 512 + lane * 8;
    bf16x8 aq[8];
#pragma unroll
    for (int i = 0; i < 8; i++) aq[i] = *(const bf16x8*)&wfq[i * 512];

    // staging geometry: lane -> (row = w*32 + i*8 + (lane>>3), phys chunk lane&7)
    // source pre-swizzle: logical chunk = (lane&7) ^ (lane>>3)   [row&7 = lane>>3]
    const int grow = lane >> 3;
    const int gch  = ((lane & 7) ^ grow) * 8;       // shorts
    // read-side swizzle (row&7 = l15&7):
    const int c0 = (quad ^ (l15 & 7)) * 8;          // logical chunk quad
    const int c1 = ((quad + 4) ^ (l15 & 7)) * 8;    // logical chunk quad+4

    for (int st = 0; st < 4; st++) {
        const int nb = ch * 512 + st * 128;
        const unsigned short* gbase =
            xT + ((size_t)b * 4096 + nb + w * 32 + grow) * 256 + gch;

        f32x4 accq[8];
#pragma unroll
        for (int i = 0; i < 8; i++) accq[i] = (f32x4)(0.f);

#pragma unroll
        for (int i = 0; i < 4; i++)            // prologue: ks=0 -> buf0
            gload16(gbase + i * 2048, Bs + w * 2048 + i * 512);
        __syncthreads();

#pragma unroll
        for (int ks = 0; ks < 4; ks++) {
            const int buf = ks & 1;
            if (ks < 3) {
                const unsigned short* gs = gbase + (ks + 1) * 64;
                unsigned short* ld = Bs + (buf ^ 1) * 8192 + w * 2048;
#pragma unroll
                for (int i = 0; i < 4; i++)
                    gload16(gs + i * 2048, ld + i * 512);
            }
            const unsigned short* bsr = Bs + buf * 8192 + l15 * 64;
#pragma unroll
            for (int nt = 0; nt < 8; nt++) {
                bf16x8 bv0 = *(const bf16x8*)&bsr[nt * 1024 + c0];
                bf16x8 bv1 = *(const bf16x8*)&bsr[nt * 1024 + c1];
                accq[nt] = __builtin_amdgcn_mfma_f32_16x16x32_bf16(aq[2 * ks], bv0, accq[nt], 0, 0, 0);
                accq[nt] = __builtin_amdgcn_mfma_f32_16x16x32_bf16(aq[2 * ks + 1], bv1, accq[nt], 0, 0, 0);
            }
            if (ks < 3) __syncthreads();
        }

        // ---- softmax over d (64 rows) -> qf fragment-major ----
#pragma unroll
        for (int nt = 0; nt < 8; nt++) {
#pragma unroll
            for (int r = 0; r < 4; r++) accq[nt][r] = __expf(accq[nt][r]);
            float s = accq[nt][0] + accq[nt][1] + accq[nt][2] + accq[nt][3];
            s += __shfl_xor(s, 16);
            s += __shfl_xor(s, 32);
            if (quad == 0) red[w * 128 + nt * 16 + l15] = s;
        }
        __syncthreads();                       // S2 (drains buf1 MFMA reads)
        if (tid < 128) {
            float t = red[tid] + red[128 + tid] + red[256 + tid] + red[384 + tid];
            red[512 + tid] = 0.125f / t;
        }
        __syncthreads();                       // S3
#pragma unroll
        for (int nt = 0; nt < 8; nt++) {
            float li = red[512 + nt * 16 + l15];
            uint2 pp;
            pp.x = (unsigned int)f2bf(accq[nt][0] * li) |
                   ((unsigned int)f2bf(accq[nt][1] * li) << 16);
            pp.y = (unsigned int)f2bf(accq[nt][2] * li) |
                   ((unsigned int)f2bf(accq[nt][3] * li) << 16);
            *(uint2*)&Qs[(nt * 16 + l15) * 72 + w * 16 + quad * 4] = pp;
        }
        __syncthreads();                       // S4
        {
            // qf granule: ((((b*32+nbIdx)*16 + ks)*8 + nt)*64 + quad*16 + l15)
            const int n = tid >> 1, half = tid & 1;
            const int nbIdx = ch * 4 + st;
            const int ksq = h * 2 + half;
            const size_t gbase2 =
                (((size_t)(b * 32 + nbIdx) * 16 + ksq) * 8 + (n >> 4)) * 64 + (n & 15);
#pragma unroll
            for (int u = 0; u < 4; u++)
                *(uint4*)&qf[(gbase2 + u * 16) * 8] = *(uint4*)&Qs[n * 72 + half * 32 + u * 8];
        }
        __syncthreads();                       // S5: Qs reads done before next staging
    }
}

// ---------------- K2b: k/v GEMM + exp(k) + phi ----------------
// grid (8 ch, 8 h, 16 b), block 256 (4 waves), BK=64
// LDS 32,768 B: Bs[2][128][64] linear; Es[64][128]|Vs[64][128] alias Bs
// (live only deposit -> phi MFMA). Fences:
//   SA (st top)     : phi reads of st-1 done before staging write
//   post-prologue + 3 in-loop dbuf barriers (vmcnt drained there)
//   SB (post ks)    : last Bs MFMA reads done before Es/Vs deposits
//   S6 (post depos) : deposits visible before phi MFMA reads
// last gload issued at ks=2, drained at ks=2 barrier -> no queue at SB.
__global__ __launch_bounds__(256, 2) void kv_phi(
    const unsigned short* __restrict__ xT, const unsigned short* __restrict__ wf,
    float* __restrict__ phi, float* __restrict__ lsum)
{
    const int ch = blockIdx.x;
    const int h  = blockIdx.y;
    const int b  = blockIdx.z;
    const int tid  = threadIdx.x;
    const int lane = tid & 63;
    const int w    = tid >> 6;
    const int quad = lane >> 4;
    const int l15  = lane & 15;

    __shared__ unsigned short smem[16384];     // 32,768 B
    unsigned short* Es = smem;                 // [64][128]
    unsigned short* Vs = smem + 8192;          // [64][128]
    unsigned short* Bs = smem;                 // [2][128][64] (aliases Es/Vs)

    const unsigned short* wfk = wf + ((size_t)((1 * 8 + h) * 4 + w) * 8) * 512 + lane * 8;
    const unsigned short* wfv = wf + ((size_t)((2 * 8 + h) * 4 + w) * 8) * 512 + lane * 8;

    f32x4 pacc[4];
#pragma unroll
    for (int i = 0; i < 4; i++) pacc[i] = (f32x4)(0.f);
    float lacc[4] = {0.f, 0.f, 0.f, 0.f};

    const int grow = lane >> 3;
    const int gch  = ((lane & 7) ^ grow) * 8;
    const int c0 = (quad ^ (l15 & 7)) * 8;
    const int c1 = ((quad + 4) ^ (l15 & 7)) * 8;

    for (int st = 0; st < 4; st++) {
        const int nb = ch * 512 + st * 128;
        const unsigned short* gbase =
            xT + ((size_t)b * 4096 + nb + w * 32 + grow) * 256 + gch;

        f32x4 acck[8], accv[8];
#pragma unroll
        for (int i = 0; i < 8; i++) {
            acck[i] = (f32x4)(0.f); accv[i] = (f32x4)(0.f);
        }

        __syncthreads();                       // SA: phi reads (st-1) done
#pragma unroll
        for (int i = 0; i < 4; i++)            // prologue: ks=0 -> buf0
            gload16(gbase + i * 2048, Bs + w * 2048 + i * 512);
        __syncthreads();

#pragma unroll
        for (int ks = 0; ks < 4; ks++) {
            const int buf = ks & 1;
            if (ks < 3) {
                const unsigned short* gs = gbase + (ks + 1) * 64;
                unsigned short* ld = Bs + (buf ^ 1) * 8192 + w * 2048;
#pragma unroll
                for (int i = 0; i < 4; i++)
                    gload16(gs + i * 2048, ld + i * 512);
            }
            bf16x8 ak0 = *(const bf16x8*)&wfk[(2 * ks) * 512];
            bf16x8 ak1 = *(const bf16x8*)&wfk[(2 * ks + 1) * 512];
            bf16x8 av0 = *(const bf16x8*)&wfv[(2 * ks) * 512];
            bf16x8 av1 = *(const bf16x8*)&wfv[(2 * ks + 1) * 512];
            const unsigned short* bsr = Bs + buf * 8192 + l15 * 64;
#pragma unroll
            for (int nt = 0; nt < 8; nt++) {
                bf16x8 bv0 = *(const bf16x8*)&bsr[nt * 1024 + c0];
                bf16x8 bv1 = *(const bf16x8*)&bsr[nt * 1024 + c1];
                acck[nt] = __builtin_amdgcn_mfma_f32_16x16x32_bf16(ak0, bv0, acck[nt], 0, 0, 0);
                accv[nt] = __builtin_amdgcn_mfma_f32_16x16x32_bf16(av0, bv0, accv[nt], 0, 0, 0);
                acck[nt] = __builtin_amdgcn_mfma_f32_16x16x32_bf16(ak1, bv1, acck[nt], 0, 0, 0);
                accv[nt] = __builtin_amdgcn_mfma_f32_16x16x32_bf16(av1, bv1, accv[nt], 0, 0, 0);
            }
            if (ks < 3) __syncthreads();
        }
        __syncthreads();                       // SB: Bs reads done

        // ---- k/v epilogue: exp, lsum partials, swizzled deposit ----
#pragma unroll
        for (int r = 0; r < 4; r++) {
            const int dl = quad * 4 + r;                            // d & 15
            const int dbase = (w * 16 + dl) * 256 + (l15 & 7) * 2;  // byte off
#pragma unroll
            for (int nt = 0; nt < 8; nt++) {
                const int pos = (2 * nt + (l15 >> 3)) ^ dl;
                float ek = __expf(acck[nt][r]);
                lacc[r] += ek;
                *(unsigned short*)((char*)Es + dbase + pos * 16) = f2bf(ek);
                *(unsigned short*)((char*)Vs + dbase + pos * 16) = f2bf(accv[nt][r]);
            }
        }
        __syncthreads();                       // S6

        // phi MFMA: phi[d][e] += sum_n expk[d][n] v[e][n], K=128
#pragma unroll
        for (int k2 = 0; k2 < 4; k2++) {
            bf16x8 ae = *(bf16x8*)((char*)Es + (w * 16 + l15) * 256 +
                                   (((k2 * 4 + quad) ^ l15) * 16));
#pragma unroll
            for (int et = 0; et < 4; et++) {
                bf16x8 bv = *(bf16x8*)((char*)Vs + (et * 16 + l15) * 256 +
                                       (((k2 * 4 + quad) ^ l15) * 16));
                pacc[et] = __builtin_amdgcn_mfma_f32_16x16x32_bf16(ae, bv, pacc[et], 0, 0, 0);
            }
        }
        // next st: SA fences Es/Vs reads before new staging
    }

    // lsum: reduce over l15 then one atomic per d-row
#pragma unroll
    for (int r = 0; r < 4; r++) {
        float s = lacc[r];
        s += __shfl_xor(s, 1); s += __shfl_xor(s, 2);
        s += __shfl_xor(s, 4); s += __shfl_xor(s, 8);
        if (l15 == 0)
            atomicAdd(&lsum[((size_t)b * 8 + h) * 64 + w * 16 + quad * 4 + r], s);
    }
    float* pp = phi + ((size_t)b * 8 + h) * 4096;
#pragma unroll
    for (int et = 0; et < 4; et++)
#pragma unroll
        for (int r = 0; r < 4; r++)
            atomicAdd(&pp[(w * 16 + quad * 4 + r) * 64 + et * 16 + l15], pacc[et][r]);
}

// ---------------- K3: Mf = w_out · (phi/l), fragment-major bf16 ----------------
// grid (8 h, 16 b), block 256 (thread = c)
__global__ __launch_bounds__(256) void build_M(
    const float* __restrict__ phi, const float* __restrict__ lsum,
    const float* __restrict__ w_out, unsigned short* __restrict__ Mf)
{
    const int h = blockIdx.x, b = blockIdx.y;
    __shared__ float pT[64][68];  // [e][d]
    const float* pp = phi + ((size_t)b * 8 + h) * 4096;  // [d][e]
    const int tid = threadIdx.x;
    const int row = tid >> 2, ls = tid & 3;
#pragma unroll
    for (int u = 0; u < 4; u++) {
        int e0 = (ls + u * 4) * 4;
        float4 v = *(const float4*)&pp[row * 64 + e0];
        pT[e0 + 0][row] = v.x; pT[e0 + 1][row] = v.y;
        pT[e0 + 2][row] = v.z; pT[e0 + 3][row] = v.w;
    }
    __syncthreads();
    const int c = tid;
    float acc[64];
#pragma unroll
    for (int d = 0; d < 64; d++) acc[d] = 0.f;
    for (int e4 = 0; e4 < 16; e4++) {
        float4 wv = *(const float4*)&w_out[(size_t)c * 512 + h * 64 + e4 * 4];
        float wq[4] = {wv.x, wv.y, wv.z, wv.w};
#pragma unroll
        for (int qq = 0; qq < 4; qq++) {
            int e = e4 * 4 + qq;
#pragma unroll
            for (int d4 = 0; d4 < 16; d4++) {
                float4 p = *(const float4*)&pT[e][d4 * 4];
                acc[d4 * 4 + 0] += wq[qq] * p.x;
                acc[d4 * 4 + 1] += wq[qq] * p.y;
                acc[d4 * 4 + 2] += wq[qq] * p.z;
                acc[d4 * 4 + 3] += wq[qq] * p.w;
            }
        }
    }
    const float* lrow = lsum + ((size_t)b * 8 + h) * 64;
    unsigned short tmp[64];
#pragma unroll
    for (int d = 0; d < 64; d++) tmp[d] = f2bf(acc[d] / lrow[d]);
    // Mf granule: ((((b*2+ct)*2+wr)*4+mi)*16 + ks)*64 + quad*16 + l15c
    const int ct = c >> 7, wr = (c >> 6) & 1, mi = (c >> 4) & 3, l15c = c & 15;
#pragma unroll
    for (int u = 0; u < 8; u++) {
        const int ksA = h * 2 + (u >> 2);
        const int quadA = u & 3;
        size_t gidx = ((((size_t)(b * 2 + ct) * 2 + wr) * 4 + mi) * 16 + ksA) * 64
                      + quadA * 16 + l15c;
        *(uint4*)&Mf[gidx * 8] = *(uint4*)&tmp[u * 8];
    }
}

// ---------------- K4: out = M · q, LDS-free, all-coalesced ----------------
// grid (32 nblocks, 2 ctiles, 16 b), block 256 (4 waves, 2x2)
__global__ __launch_bounds__(256, 3) void out_mfma(
    const unsigned short* __restrict__ Mf, const unsigned short* __restrict__ qf,
    float* __restrict__ out)
{
    const int nbIdx = blockIdx.x;
    const int ct    = blockIdx.y;
    const int b     = blockIdx.z;
    const int tid  = threadIdx.x;
    const int lane = tid & 63;
    const int w    = tid >> 6;
    const int wr   = w >> 1, wc = w & 1;
    const int quad = lane >> 4;
    const int l15  = lane & 15;

    f32x4 acc[4][4];
#pragma unroll
    for (int i = 0; i < 4; i++)
#pragma unroll
        for (int j = 0; j < 4; j++) acc[i][j] = (f32x4)(0.f);

    const unsigned short* Ab =
        Mf + ((((size_t)(b * 2 + ct) * 2 + wr) * 4) * 16) * 512 + lane * 8;
    const unsigned short* Bb =
        qf + (((size_t)(b * 32 + nbIdx) * 16) * 8) * 512 + lane * 8;

    for (int ks = 0; ks < 16; ks++) {
        bf16x8 af[4], bv[4];
#pragma unroll
        for (int mi = 0; mi < 4; mi++)
            af[mi] = *(const bf16x8*)&Ab[(size_t)(mi * 16 + ks) * 512];
#pragma unroll
        for (int ni = 0; ni < 4; ni++)
            bv[ni] = *(const bf16x8*)&Bb[(size_t)(ks * 8 + wc * 4 + ni) * 512];
#pragma unroll
        for (int mi = 0; mi < 4; mi++)
#pragma unroll
            for (int ni = 0; ni < 4; ni++)
                acc[mi][ni] = __builtin_amdgcn_mfma_f32_16x16x32_bf16(
                    af[mi], bv[ni], acc[mi][ni], 0, 0, 0);
    }
    float* ob = out + ((size_t)b * 256 + ct * 128 + wr * 64) * 4096
                + nbIdx * 128 + wc * 64;
#pragma unroll
    for (int mi = 0; mi < 4; mi++)
#pragma unroll
        for (int ni = 0; ni < 4; ni++)
#pragma unroll
            for (int r = 0; r < 4; r++)
                ob[(size_t)(mi * 16 + quad * 4 + r) * 4096 + ni * 16 + l15]
                    = acc[mi][ni][r];
}

extern "C" void kernel_launch(void* const* d_in, const int* in_sizes, int n_in,
                              void* d_out, int out_size, void* d_ws, size_t ws_size,
                              hipStream_t stream) {
    const float* x     = (const float*)d_in[0];
    const float* w_qkv = (const float*)d_in[1];
    const float* w_out = (const float*)d_in[2];
    float* out = (float*)d_out;

    char* ws = (char*)d_ws;
    unsigned short* qf = (unsigned short*)ws;                     // 67,108,864 B
    unsigned short* wf = (unsigned short*)(ws + 67108864);        //    786,432 B
    float* lsum = (float*)(ws + 67895296);                        //     32,768 B
    float* phi  = (float*)(ws + 67928064);                        //  2,097,152 B
    unsigned short* Mf = (unsigned short*)(ws + 70025216);        //  4,194,304 B
    unsigned short* xT = (unsigned short*)(ws + 74219520);        // 33,554,432 B
    // total ws: 107,773,952 B (same as R6, proven safe)

    hipMemsetAsync(lsum, 0, (8192 + 524288) * sizeof(float), stream);

    cvt_w_frag<<<192, 256, 0, stream>>>(w_qkv, wf);
    cvt_xT<<<dim3(64, 4, 16), 256, 0, stream>>>(x, xT);
    q_gemm<<<dim3(8, 8, 16), 256, 0, stream>>>(xT, wf, qf);
    kv_phi<<<dim3(8, 8, 16), 256, 0, stream>>>(xT, wf, phi, lsum);
    build_M<<<dim3(8, 16), 256, 0, stream>>>(phi, lsum, w_out, Mf);
    out_mfma<<<dim3(32, 2, 16), 256, 0, stream>>>(Mf, qf, out);
}